// Round 12
// baseline (7045.245 us; speedup 1.0000x reference)
//
#include <hip/hip_runtime.h>
#include <hip/hip_bf16.h>

typedef __hip_bfloat16 bf16;

// ---------- helpers ----------
__device__ __forceinline__ float bf2f(bf16 v) { return __bfloat162float(v); }

__device__ __forceinline__ float2 bfpair(unsigned u) {
    float2 r;
    r.x = __uint_as_float(u << 16);
    r.y = __uint_as_float(u & 0xffff0000u);
    return r;
}

__device__ __forceinline__ unsigned short f2bf_bits(float f) {
    unsigned u = __float_as_uint(f);
    return (unsigned short)((u + 0x7fffu + ((u >> 16) & 1u)) >> 16);
}

// unpack 16 bf16 (one head slice) from a 128-elem bf16 row
__device__ __forceinline__ void unpack16(const uint4* row, int h, float* f) {
    uint4 u0 = row[h * 2 + 0];
    uint4 u1 = row[h * 2 + 1];
    float2 t;
    t = bfpair(u0.x); f[0] = t.x;  f[1] = t.y;
    t = bfpair(u0.y); f[2] = t.x;  f[3] = t.y;
    t = bfpair(u0.z); f[4] = t.x;  f[5] = t.y;
    t = bfpair(u0.w); f[6] = t.x;  f[7] = t.y;
    t = bfpair(u1.x); f[8] = t.x;  f[9] = t.y;
    t = bfpair(u1.y); f[10] = t.x; f[11] = t.y;
    t = bfpair(u1.z); f[12] = t.x; f[13] = t.y;
    t = bfpair(u1.w); f[14] = t.x; f[15] = t.y;
}

// ---------- utility: zero fill (graph-capture-safe replacement for memset) ----------
__global__ __launch_bounds__(256) void zero_k(float* __restrict__ p, long long n) {
    long long i = (long long)blockIdx.x * 256 + threadIdx.x;
    long long st = (long long)gridDim.x * 256;
    for (; i < n; i += st) p[i] = 0.f;
}

// ---------- canonicalize edge_index to int32 [2,E] (handles int32 or int64 input) ----------
__global__ __launch_bounds__(256) void canon_ei_k(const unsigned* __restrict__ src,
                                                  int* __restrict__ dst, int twoE) {
    __shared__ int s_is64;
    if (threadIdx.x == 0) {
        bool a = true;
        for (int j = 1; j < 512; j += 2) a = a && (src[j] == 0u);  // int64 LE: high words zero
        s_is64 = a ? 1 : 0;
    }
    __syncthreads();
    bool is64 = (s_is64 != 0);
    long long i = (long long)blockIdx.x * 256 + threadIdx.x;
    long long st = (long long)gridDim.x * 256;
    if (is64) { for (; i < twoE; i += st) dst[i] = (int)src[2 * i]; }
    else      { for (; i < twoE; i += st) dst[i] = (int)src[i]; }
}

// ---------- LN stats: one wave per 128-elem fp32 row; mu/rstd out ----------
__global__ __launch_bounds__(256) void ln_stats_k(const float* __restrict__ x,
                                                  float* __restrict__ mu,
                                                  float* __restrict__ rs, int M) {
    int row = blockIdx.x * 4 + (threadIdx.x >> 6);
    if (row >= M) return;
    int lane = threadIdx.x & 63;
    float2 f = ((const float2*)x)[(size_t)row * 64 + lane];
    float s = f.x + f.y;
    #pragma unroll
    for (int off = 32; off > 0; off >>= 1) s += __shfl_xor(s, off);
    float mean = s * (1.0f / 128.0f);
    float d0 = f.x - mean, d1 = f.y - mean;
    float vs = d0 * d0 + d1 * d1;
    #pragma unroll
    for (int off = 32; off > 0; off >>= 1) vs += __shfl_xor(vs, off);
    float rstd = rsqrtf(vs * (1.0f / 128.0f) + 1e-5f);
    if (lane == 0) { mu[row] = mean; rs[row] = rstd; }
}

// ---------- tiled GEMM: C[M,N] = A'[M,K] @ B[K,N] + bias (+epilogue) ----------
// AMODE 0: A bf16   1: A fp32   2: A = LN(fp32 row)
// EPI 0: none   1: gelu   2: +res fp32 (may alias Cp elementwise)
// OUTF32: write fp32 else bf16
#define BM 64
#define BN 64
#define BKT 32

template <int AMODE, int EPI, bool OUTF32>
__global__ __launch_bounds__(256) void gemm_k(const void* __restrict__ Ap,
                                              const float* __restrict__ mu,
                                              const float* __restrict__ rs,
                                              const float* __restrict__ lg,
                                              const float* __restrict__ lb,
                                              const float* __restrict__ B,
                                              const float* __restrict__ bias,
                                              const float* resp,
                                              void* Cp,
                                              int M, int N, int K) {
    __shared__ float As[BM][BKT + 1];
    __shared__ float Bs[BKT][BN + 1];
    int tid = threadIdx.x;
    int m0 = blockIdx.y * BM, n0 = blockIdx.x * BN;
    int tx = tid & 15, ty = tid >> 4;
    float acc[4][4] = {};

    for (int k0 = 0; k0 < K; k0 += BKT) {
        #pragma unroll
        for (int i = 0; i < 8; i++) {
            int idx = tid + i * 256;
            int r = idx >> 5, c = idx & 31;
            int m = m0 + r;
            float val = 0.f;
            if (m < M) {
                if (AMODE == 0) val = bf2f(((const bf16*)Ap)[(size_t)m * K + k0 + c]);
                else if (AMODE == 1) val = ((const float*)Ap)[(size_t)m * K + k0 + c];
                else {
                    float xv = ((const float*)Ap)[(size_t)m * K + k0 + c];
                    val = (xv - mu[m]) * rs[m] * lg[k0 + c] + lb[k0 + c];
                }
            }
            As[r][c] = val;
        }
        #pragma unroll
        for (int i = 0; i < 8; i++) {
            int idx = tid + i * 256;
            int r = idx >> 6, c = idx & 63;
            Bs[r][c] = B[(size_t)(k0 + r) * N + n0 + c];
        }
        __syncthreads();
        #pragma unroll
        for (int kk = 0; kk < BKT; kk++) {
            float a[4], bb[4];
            #pragma unroll
            for (int i = 0; i < 4; i++) a[i] = As[ty * 4 + i][kk];
            #pragma unroll
            for (int j = 0; j < 4; j++) bb[j] = Bs[kk][tx * 4 + j];
            #pragma unroll
            for (int i = 0; i < 4; i++)
                #pragma unroll
                for (int j = 0; j < 4; j++) acc[i][j] += a[i] * bb[j];
        }
        __syncthreads();
    }

    #pragma unroll
    for (int i = 0; i < 4; i++) {
        int m = m0 + ty * 4 + i;
        if (m >= M) continue;
        #pragma unroll
        for (int j = 0; j < 4; j++) {
            int n = n0 + tx * 4 + j;
            float val = acc[i][j] + bias[n];
            if (EPI == 1) val = 0.5f * val * (1.0f + erff(val * 0.70710678118f));
            if (EPI == 2) val += resp[(size_t)m * N + n];
            if (OUTF32) ((float*)Cp)[(size_t)m * N + n] = val;
            else ((unsigned short*)Cp)[(size_t)m * N + n] = f2bf_bits(val);
        }
    }
}

// ---------- edge pass 1: z[dst,h] += exp(q[dst]·k[src]/4); deg[dst]++ ----------
__global__ __launch_bounds__(256) void edge_z_k(const bf16* __restrict__ q,
                                                const bf16* __restrict__ k,
                                                const int* __restrict__ ei,
                                                float* __restrict__ z,
                                                int* __restrict__ deg, int E) {
    int e = blockIdx.x * 256 + threadIdx.x;
    if (e >= E) return;
    int s = ei[e], d = ei[E + e];
    atomicAdd(&deg[d], 1);
    const uint4* qr = (const uint4*)(q + (size_t)d * 128);
    const uint4* kr = (const uint4*)(k + (size_t)s * 128);
    #pragma unroll
    for (int h = 0; h < 8; h++) {
        float qa[16], kb[16];
        unpack16(qr, h, qa);
        unpack16(kr, h, kb);
        float dot = 0.f;
        #pragma unroll
        for (int t = 0; t < 16; t++) dot += qa[t] * kb[t];
        atomicAdd(&z[(size_t)d * 8 + h], expf(dot * 0.25f));
    }
}

// ---------- self-loop z (plain add; runs after edge_z) ----------
__global__ __launch_bounds__(256) void self_z_k(const bf16* __restrict__ q,
                                                const bf16* __restrict__ k,
                                                float* __restrict__ z, int NN) {
    int idx = blockIdx.x * 256 + threadIdx.x;
    if (idx >= NN * 8) return;
    int i = idx >> 3, h = idx & 7;
    float qa[16], kb[16];
    unpack16((const uint4*)(q + (size_t)i * 128), h, qa);
    unpack16((const uint4*)(k + (size_t)i * 128), h, kb);
    float dot = 0.f;
    #pragma unroll
    for (int t = 0; t < 16; t++) dot += qa[t] * kb[t];
    z[idx] += expf(dot * 0.25f);
}

// ---------- edge pass 2: agg[dst] += (exp(score)/z)*v[src] ----------
__global__ __launch_bounds__(256) void edge_agg_k(const bf16* __restrict__ q,
                                                  const bf16* __restrict__ k,
                                                  const bf16* __restrict__ v,
                                                  const int* __restrict__ ei,
                                                  const float* __restrict__ z,
                                                  float* __restrict__ agg, int E) {
    int idx = blockIdx.x * 256 + threadIdx.x;
    if (idx >= E * 8) return;
    int e = idx >> 3, h = idx & 7;
    int s = ei[e], d = ei[E + e];
    float qa[16], kb[16];
    unpack16((const uint4*)(q + (size_t)d * 128), h, qa);
    unpack16((const uint4*)(k + (size_t)s * 128), h, kb);
    float dot = 0.f;
    #pragma unroll
    for (int t = 0; t < 16; t++) dot += qa[t] * kb[t];
    float alpha = expf(dot * 0.25f) / z[(size_t)d * 8 + h];
    float vv[16];
    unpack16((const uint4*)(v + (size_t)s * 128), h, vv);
    float* ar = agg + (size_t)d * 128 + h * 16;
    #pragma unroll
    for (int t = 0; t < 16; t++) atomicAdd(&ar[t], alpha * vv[t]);
}

// ---------- self-loop agg + deg==0 masking ----------
__global__ __launch_bounds__(256) void self_agg_k(const bf16* __restrict__ q,
                                                  const bf16* __restrict__ k,
                                                  const bf16* __restrict__ v,
                                                  const float* __restrict__ z,
                                                  const int* __restrict__ deg,
                                                  float* __restrict__ agg, int NN) {
    int idx = blockIdx.x * 256 + threadIdx.x;
    if (idx >= NN * 8) return;
    int i = idx >> 3, h = idx & 7;
    float* ar = agg + (size_t)i * 128 + h * 16;
    if (deg[i] == 0) {
        #pragma unroll
        for (int t = 0; t < 16; t++) ar[t] = 0.f;
        return;
    }
    float qa[16], kb[16];
    unpack16((const uint4*)(q + (size_t)i * 128), h, qa);
    unpack16((const uint4*)(k + (size_t)i * 128), h, kb);
    float dot = 0.f;
    #pragma unroll
    for (int t = 0; t < 16; t++) dot += qa[t] * kb[t];
    float alpha = expf(dot * 0.25f) / z[idx];
    float vv[16];
    unpack16((const uint4*)(v + (size_t)i * 128), h, vv);
    #pragma unroll
    for (int t = 0; t < 16; t++) ar[t] += alpha * vv[t];
}

// ---------- launch ----------
extern "C" void kernel_launch(void* const* d_in, const int* in_sizes, int n_in,
                              void* d_out, int out_size, void* d_ws, size_t ws_size,
                              hipStream_t stream) {
    const float* x  = (const float*)d_in[0];   // fp32, C-order [N,128]
    const void*  eiRaw = d_in[1];              // int32 or int64 [2,E] — canonicalized below
    const float* Wq = (const float*)d_in[2];
    const float* bq = (const float*)d_in[3];
    const float* Wk = (const float*)d_in[4];
    const float* bk = (const float*)d_in[5];
    const float* Wv = (const float*)d_in[6];
    const float* bv = (const float*)d_in[7];
    const float* Wo = (const float*)d_in[8];
    const float* bo = (const float*)d_in[9];
    const float* g1 = (const float*)d_in[10];
    const float* b1 = (const float*)d_in[11];
    const float* g2 = (const float*)d_in[12];
    const float* b2 = (const float*)d_in[13];
    const float* W1 = (const float*)d_in[14];
    const float* bf1 = (const float*)d_in[15];
    const float* W2 = (const float*)d_in[16];
    const float* bf2 = (const float*)d_in[17];
    float* out = (float*)d_out;   // FP32 output (R11 evidence); also holds x1

    const int N = in_sizes[0] / 128;
    const int E = in_sizes[1] / 2;

    // workspace (~124 MB, ws >= 260 MB per R7 probe); no overlays
    char* w = (char*)d_ws;
    size_t off = 0;
    auto alloc = [&](size_t bytes) -> void* {
        void* ptr = w + off;
        off = (off + bytes + 255) & ~(size_t)255;
        return ptr;
    };
    float* z    = (float*)alloc((size_t)N * 8 * 4);
    int*   deg  = (int*)alloc((size_t)N * 4);
    size_t zdeg_words = off / 4;
    int*   ei32 = (int*)alloc((size_t)E * 2 * 4);
    float* mu   = (float*)alloc((size_t)N * 4);
    float* rs   = (float*)alloc((size_t)N * 4);
    bf16*  qb   = (bf16*)alloc((size_t)N * 128 * 2);
    bf16*  kb   = (bf16*)alloc((size_t)N * 128 * 2);
    bf16*  vb   = (bf16*)alloc((size_t)N * 128 * 2);
    float* agg  = (float*)alloc((size_t)N * 128 * 4);
    bf16*  t    = (bf16*)alloc((size_t)N * 512 * 2);
    (void)ws_size; (void)n_in; (void)out_size;

    // 0. zero z/deg/agg (kernels, NOT memsetAsync — graph-capture safety) + canonicalize ei
    zero_k<<<1024, 256, 0, stream>>>((float*)z, (long long)zdeg_words);
    zero_k<<<2048, 256, 0, stream>>>(agg, (long long)N * 128);
    canon_ei_k<<<2048, 256, 0, stream>>>((const unsigned*)eiRaw, ei32, E * 2);

    int lnBlocks = (N + 3) / 4;
    dim3 gQKV(128 / BN, (N + BM - 1) / BM);
    dim3 gFFN(512 / BN, (N + BM - 1) / BM);

    // 1. LN1 stats on x
    ln_stats_k<<<lnBlocks, 256, 0, stream>>>(x, mu, rs, N);
    // 2. q,k,v = LN1(x) @ W + b  (LN fused into A-load; bf16 staging)
    gemm_k<2, 0, false><<<gQKV, 256, 0, stream>>>(x, mu, rs, g1, b1, Wq, bq, nullptr, qb, N, 128, 128);
    gemm_k<2, 0, false><<<gQKV, 256, 0, stream>>>(x, mu, rs, g1, b1, Wk, bk, nullptr, kb, N, 128, 128);
    gemm_k<2, 0, false><<<gQKV, 256, 0, stream>>>(x, mu, rs, g1, b1, Wv, bv, nullptr, vb, N, 128, 128);
    // 3. z += exp(scores) over edges (atomic) + deg
    edge_z_k<<<(E + 255) / 256, 256, 0, stream>>>(qb, kb, ei32, z, deg, E);
    // 4. z += exp(self score)
    self_z_k<<<(N * 8 + 255) / 256, 256, 0, stream>>>(qb, kb, z, N);
    // 5. agg += alpha * v over edges (atomic; score recomputed)
    edge_agg_k<<<(E * 8 + 255) / 256, 256, 0, stream>>>(qb, kb, vb, ei32, z, agg, E);
    // 6. self-loop agg + deg==0 masking
    self_agg_k<<<(N * 8 + 255) / 256, 256, 0, stream>>>(qb, kb, vb, z, deg, agg, N);
    // 7. x1 = x + agg @ Wo + bo  -> d_out (fp32)
    gemm_k<1, 2, true><<<gQKV, 256, 0, stream>>>(agg, nullptr, nullptr, nullptr, nullptr,
                                                 Wo, bo, x, out, N, 128, 128);
    // 8. LN2 stats on x1
    ln_stats_k<<<lnBlocks, 256, 0, stream>>>(out, mu, rs, N);
    // 9. t = gelu(LN2(x1) @ W1 + bf1)  (bf16 staging)
    gemm_k<2, 1, false><<<gFFN, 256, 0, stream>>>(out, mu, rs, g2, b2, W1, bf1, nullptr, t, N, 512, 128);
    // 10. out = x1 + t @ W2 + bf2  (fp32; res aliases out elementwise — safe)
    gemm_k<0, 2, true><<<gQKV, 256, 0, stream>>>(t, nullptr, nullptr, nullptr, nullptr,
                                                 W2, bf2, out, out, N, 128, 512);
}

// Round 13
// 1075.439 us; speedup vs baseline: 6.5510x; 6.5510x over previous
//
#include <hip/hip_runtime.h>
#include <hip/hip_bf16.h>

typedef __hip_bfloat16 bf16;

// ---------- helpers ----------
__device__ __forceinline__ float bf2f(bf16 v) { return __bfloat162float(v); }

__device__ __forceinline__ float2 bfpair(unsigned u) {
    float2 r;
    r.x = __uint_as_float(u << 16);
    r.y = __uint_as_float(u & 0xffff0000u);
    return r;
}

__device__ __forceinline__ unsigned short f2bf_bits(float f) {
    unsigned u = __float_as_uint(f);
    return (unsigned short)((u + 0x7fffu + ((u >> 16) & 1u)) >> 16);
}

// ---------- utility: zero fill (graph-capture-safe) ----------
__global__ __launch_bounds__(256) void zero_k(float* __restrict__ p, long long n) {
    long long i = (long long)blockIdx.x * 256 + threadIdx.x;
    long long st = (long long)gridDim.x * 256;
    for (; i < n; i += st) p[i] = 0.f;
}

// ---------- canonicalize edge_index to int32 [2,E] (int32 or int64 input) ----------
__global__ __launch_bounds__(256) void canon_ei_k(const unsigned* __restrict__ src,
                                                  int* __restrict__ dst, int twoE) {
    __shared__ int s_is64;
    if (threadIdx.x == 0) {
        bool a = true;
        for (int j = 1; j < 512; j += 2) a = a && (src[j] == 0u);
        s_is64 = a ? 1 : 0;
    }
    __syncthreads();
    bool is64 = (s_is64 != 0);
    long long i = (long long)blockIdx.x * 256 + threadIdx.x;
    long long st = (long long)gridDim.x * 256;
    if (is64) { for (; i < twoE; i += st) dst[i] = (int)src[2 * i]; }
    else      { for (; i < twoE; i += st) dst[i] = (int)src[i]; }
}

// ---------- CSR build ----------
__global__ __launch_bounds__(256) void count_deg_k(const int* __restrict__ ei,
                                                   int* __restrict__ deg, int E) {
    int e = blockIdx.x * 256 + threadIdx.x;
    if (e < E) atomicAdd(&deg[ei[E + e]], 1);
}

#define SCAN_BLK 1024
__global__ __launch_bounds__(256) void scan1_k(const int* __restrict__ deg,
                                               int* __restrict__ off,
                                               int* __restrict__ bsum, int n) {
    __shared__ int s[256];
    int base = blockIdx.x * SCAN_BLK;
    int t = threadIdx.x;
    int v[4]; int sum = 0;
    #pragma unroll
    for (int j = 0; j < 4; j++) {
        int idx = base + t * 4 + j;
        v[j] = (idx < n) ? deg[idx] : 0;
        sum += v[j];
    }
    s[t] = sum; __syncthreads();
    for (int o = 1; o < 256; o <<= 1) {
        int add = (t >= o) ? s[t - o] : 0;
        __syncthreads();
        s[t] += add;
        __syncthreads();
    }
    int run = (t > 0) ? s[t - 1] : 0;
    if (t == 255) bsum[blockIdx.x] = s[255];
    #pragma unroll
    for (int j = 0; j < 4; j++) {
        int idx = base + t * 4 + j;
        if (idx < n) off[idx] = run;
        run += v[j];
    }
}

__global__ __launch_bounds__(64) void scan2_k(int* __restrict__ bsum, int nb) {
    int t = threadIdx.x;
    int own = (t < nb) ? bsum[t] : 0;
    int v = own;
    #pragma unroll
    for (int o = 1; o < 64; o <<= 1) {
        int u = __shfl_up(v, o);
        if (t >= o) v += u;
    }
    if (t < nb) bsum[t] = v - own;   // exclusive
}

__global__ __launch_bounds__(256) void scan3_k(int* __restrict__ off,
                                               int* __restrict__ cursor,
                                               const int* __restrict__ bsum, int n) {
    int i = blockIdx.x * 256 + threadIdx.x;
    if (i < n) {
        int o = off[i] + bsum[i / SCAN_BLK];
        off[i] = o;
        cursor[i] = o;
    }
}

__global__ __launch_bounds__(256) void scatter_k(const int* __restrict__ ei,
                                                 int* __restrict__ cursor,
                                                 int* __restrict__ csr, int E) {
    int e = blockIdx.x * 256 + threadIdx.x;
    if (e >= E) return;
    int s = ei[e], d = ei[E + e];
    int pos = atomicAdd(&cursor[d], 1);
    csr[pos] = s;
}

// ---------- LN stats: one wave per 128-elem fp32 row ----------
__global__ __launch_bounds__(256) void ln_stats_k(const float* __restrict__ x,
                                                  float* __restrict__ mu,
                                                  float* __restrict__ rs, int M) {
    int row = blockIdx.x * 4 + (threadIdx.x >> 6);
    if (row >= M) return;
    int lane = threadIdx.x & 63;
    float2 f = ((const float2*)x)[(size_t)row * 64 + lane];
    float s = f.x + f.y;
    #pragma unroll
    for (int off = 32; off > 0; off >>= 1) s += __shfl_xor(s, off);
    float mean = s * (1.0f / 128.0f);
    float d0 = f.x - mean, d1 = f.y - mean;
    float vs = d0 * d0 + d1 * d1;
    #pragma unroll
    for (int off = 32; off > 0; off >>= 1) vs += __shfl_xor(vs, off);
    float rstd = rsqrtf(vs * (1.0f / 128.0f) + 1e-5f);
    if (lane == 0) { mu[row] = mean; rs[row] = rstd; }
}

// ---------- tiled GEMM (unchanged from R12) ----------
// AMODE 0: A bf16   1: A fp32   2: A = LN(fp32 row)
// EPI 0: none   1: gelu   2: +res fp32 (may alias Cp elementwise)
#define BM 64
#define BN 64
#define BKT 32

template <int AMODE, int EPI, bool OUTF32>
__global__ __launch_bounds__(256) void gemm_k(const void* __restrict__ Ap,
                                              const float* __restrict__ mu,
                                              const float* __restrict__ rs,
                                              const float* __restrict__ lg,
                                              const float* __restrict__ lb,
                                              const float* __restrict__ B,
                                              const float* __restrict__ bias,
                                              const float* resp,
                                              void* Cp,
                                              int M, int N, int K) {
    __shared__ float As[BM][BKT + 1];
    __shared__ float Bs[BKT][BN + 1];
    int tid = threadIdx.x;
    int m0 = blockIdx.y * BM, n0 = blockIdx.x * BN;
    int tx = tid & 15, ty = tid >> 4;
    float acc[4][4] = {};

    for (int k0 = 0; k0 < K; k0 += BKT) {
        #pragma unroll
        for (int i = 0; i < 8; i++) {
            int idx = tid + i * 256;
            int r = idx >> 5, c = idx & 31;
            int m = m0 + r;
            float val = 0.f;
            if (m < M) {
                if (AMODE == 0) val = bf2f(((const bf16*)Ap)[(size_t)m * K + k0 + c]);
                else if (AMODE == 1) val = ((const float*)Ap)[(size_t)m * K + k0 + c];
                else {
                    float xv = ((const float*)Ap)[(size_t)m * K + k0 + c];
                    val = (xv - mu[m]) * rs[m] * lg[k0 + c] + lb[k0 + c];
                }
            }
            As[r][c] = val;
        }
        #pragma unroll
        for (int i = 0; i < 8; i++) {
            int idx = tid + i * 256;
            int r = idx >> 6, c = idx & 63;
            Bs[r][c] = B[(size_t)(k0 + r) * N + n0 + c];
        }
        __syncthreads();
        #pragma unroll
        for (int kk = 0; kk < BKT; kk++) {
            float a[4], bb[4];
            #pragma unroll
            for (int i = 0; i < 4; i++) a[i] = As[ty * 4 + i][kk];
            #pragma unroll
            for (int j = 0; j < 4; j++) bb[j] = Bs[kk][tx * 4 + j];
            #pragma unroll
            for (int i = 0; i < 4; i++)
                #pragma unroll
                for (int j = 0; j < 4; j++) acc[i][j] += a[i] * bb[j];
        }
        __syncthreads();
    }

    #pragma unroll
    for (int i = 0; i < 4; i++) {
        int m = m0 + ty * 4 + i;
        if (m >= M) continue;
        #pragma unroll
        for (int j = 0; j < 4; j++) {
            int n = n0 + tx * 4 + j;
            float val = acc[i][j] + bias[n];
            if (EPI == 1) val = 0.5f * val * (1.0f + erff(val * 0.70710678118f));
            if (EPI == 2) val += resp[(size_t)m * N + n];
            if (OUTF32) ((float*)Cp)[(size_t)m * N + n] = val;
            else ((unsigned short*)Cp)[(size_t)m * N + n] = f2bf_bits(val);
        }
    }
}

// ---------- node aggregation: one wave per dst node, CSR gather, no atomics ----------
// lane owns 2 dims (lane*2, lane*2+1); head = lane>>3; 8-lane shuffle-reduce for dot.
__global__ __launch_bounds__(256) void node_agg_k(const bf16* __restrict__ q,
                                                  const bf16* __restrict__ k,
                                                  const bf16* __restrict__ v,
                                                  const int* __restrict__ off,
                                                  const int* __restrict__ deg,
                                                  const int* __restrict__ csr,
                                                  float* __restrict__ agg, int NN) {
    int node = blockIdx.x * 4 + (threadIdx.x >> 6);
    if (node >= NN) return;
    int lane = threadIdx.x & 63;
    float2 qf = bfpair(((const unsigned*)(q + (size_t)node * 128))[lane]);
    int start = off[node];
    int cnt = deg[node];
    float acc0 = 0.f, acc1 = 0.f, zsum = 0.f;
    for (int e = 0; e <= cnt; e++) {
        int s = (e < cnt) ? csr[start + e] : node;   // final iteration = self-loop
        float2 kf = bfpair(((const unsigned*)(k + (size_t)s * 128))[lane]);
        float dot = qf.x * kf.x + qf.y * kf.y;
        dot += __shfl_xor(dot, 1);
        dot += __shfl_xor(dot, 2);
        dot += __shfl_xor(dot, 4);                    // 8-lane (one head) reduce
        float p = __expf(dot * 0.25f);
        zsum += p;
        float2 vf = bfpair(((const unsigned*)(v + (size_t)s * 128))[lane]);
        acc0 += p * vf.x;
        acc1 += p * vf.y;
    }
    float2 o;
    if (cnt == 0) { o.x = 0.f; o.y = 0.f; }
    else { float inv = 1.0f / zsum; o.x = acc0 * inv; o.y = acc1 * inv; }
    ((float2*)agg)[(size_t)node * 64 + lane] = o;
}

// ---------- launch ----------
extern "C" void kernel_launch(void* const* d_in, const int* in_sizes, int n_in,
                              void* d_out, int out_size, void* d_ws, size_t ws_size,
                              hipStream_t stream) {
    const float* x  = (const float*)d_in[0];   // fp32, C-order [N,128]
    const void*  eiRaw = d_in[1];
    const float* Wq = (const float*)d_in[2];
    const float* bq = (const float*)d_in[3];
    const float* Wk = (const float*)d_in[4];
    const float* bk = (const float*)d_in[5];
    const float* Wv = (const float*)d_in[6];
    const float* bv = (const float*)d_in[7];
    const float* Wo = (const float*)d_in[8];
    const float* bo = (const float*)d_in[9];
    const float* g1 = (const float*)d_in[10];
    const float* b1 = (const float*)d_in[11];
    const float* g2 = (const float*)d_in[12];
    const float* b2 = (const float*)d_in[13];
    const float* W1 = (const float*)d_in[14];
    const float* bf1 = (const float*)d_in[15];
    const float* W2 = (const float*)d_in[16];
    const float* bf2 = (const float*)d_in[17];
    float* out = (float*)d_out;   // fp32 output; also holds x1

    const int N = in_sizes[0] / 128;
    const int E = in_sizes[1] / 2;

    char* w = (char*)d_ws;
    size_t off_b = 0;
    auto alloc = [&](size_t bytes) -> void* {
        void* ptr = w + off_b;
        off_b = (off_b + bytes + 255) & ~(size_t)255;
        return ptr;
    };
    int*   deg    = (int*)alloc((size_t)N * 4);
    int*   offA   = (int*)alloc((size_t)N * 4);
    int*   cursor = (int*)alloc((size_t)N * 4);
    int*   bsum   = (int*)alloc(64 * 4);
    int*   ei32   = (int*)alloc((size_t)E * 2 * 4);
    int*   csr    = (int*)alloc((size_t)E * 4);
    float* mu     = (float*)alloc((size_t)N * 4);
    float* rs     = (float*)alloc((size_t)N * 4);
    bf16*  qb     = (bf16*)alloc((size_t)N * 128 * 2);
    bf16*  kb     = (bf16*)alloc((size_t)N * 128 * 2);
    bf16*  vb     = (bf16*)alloc((size_t)N * 128 * 2);
    float* agg    = (float*)alloc((size_t)N * 128 * 4);
    bf16*  t      = (bf16*)alloc((size_t)N * 512 * 2);
    (void)ws_size; (void)n_in; (void)out_size;

    int nb = (N + SCAN_BLK - 1) / SCAN_BLK;   // 49 for N=50000 (<=64)

    // CSR build
    zero_k<<<64, 256, 0, stream>>>((float*)deg, N);
    canon_ei_k<<<2048, 256, 0, stream>>>((const unsigned*)eiRaw, ei32, E * 2);
    count_deg_k<<<(E + 255) / 256, 256, 0, stream>>>(ei32, deg, E);
    scan1_k<<<nb, 256, 0, stream>>>(deg, offA, bsum, N);
    scan2_k<<<1, 64, 0, stream>>>(bsum, nb);
    scan3_k<<<(N + 255) / 256, 256, 0, stream>>>(offA, cursor, bsum, N);
    scatter_k<<<(E + 255) / 256, 256, 0, stream>>>(ei32, cursor, csr, E);

    int lnBlocks = (N + 3) / 4;
    dim3 gQKV(128 / BN, (N + BM - 1) / BM);
    dim3 gFFN(512 / BN, (N + BM - 1) / BM);

    // 1. LN1 stats on x
    ln_stats_k<<<lnBlocks, 256, 0, stream>>>(x, mu, rs, N);
    // 2. q,k,v = LN1(x) @ W + b  (LN fused; bf16 staging)
    gemm_k<2, 0, false><<<gQKV, 256, 0, stream>>>(x, mu, rs, g1, b1, Wq, bq, nullptr, qb, N, 128, 128);
    gemm_k<2, 0, false><<<gQKV, 256, 0, stream>>>(x, mu, rs, g1, b1, Wk, bk, nullptr, kb, N, 128, 128);
    gemm_k<2, 0, false><<<gQKV, 256, 0, stream>>>(x, mu, rs, g1, b1, Wv, bv, nullptr, vb, N, 128, 128);
    // 3. segment softmax + aggregation via CSR gather (no atomics)
    node_agg_k<<<(N + 3) / 4, 256, 0, stream>>>(qb, kb, vb, offA, deg, csr, agg, N);
    // 4. x1 = x + agg @ Wo + bo  -> d_out (fp32)
    gemm_k<1, 2, true><<<gQKV, 256, 0, stream>>>(agg, nullptr, nullptr, nullptr, nullptr,
                                                 Wo, bo, x, out, N, 128, 128);
    // 5. LN2 stats on x1
    ln_stats_k<<<lnBlocks, 256, 0, stream>>>(out, mu, rs, N);
    // 6. t = gelu(LN2(x1) @ W1 + bf1)  (bf16 staging)
    gemm_k<2, 1, false><<<gFFN, 256, 0, stream>>>(out, mu, rs, g2, b2, W1, bf1, nullptr, t, N, 512, 128);
    // 7. out = x1 + t @ W2 + bf2  (fp32; res aliases out elementwise — safe)
    gemm_k<0, 2, true><<<gQKV, 256, 0, stream>>>(t, nullptr, nullptr, nullptr, nullptr,
                                                 W2, bf2, out, out, N, 128, 512);
}